// Round 7
// baseline (838.082 us; speedup 1.0000x reference)
//
#include <hip/hip_runtime.h>

#define FEAT 256
#define BN_EPS 1e-5f

typedef __attribute__((ext_vector_type(8))) short short8v;  // 8 bf16 = 4 VGPRs
typedef __attribute__((ext_vector_type(4))) float f32x4;    // MFMA C/D

static __device__ __forceinline__ float frelu(float x) { return fmaxf(x, 0.f); }

// bf16 round-to-nearest-even split helpers (manual, no header dependence)
static __device__ __forceinline__ unsigned short bf16_rne(float f) {
    unsigned u = __float_as_uint(f);
    unsigned r = u + 0x7FFFu + ((u >> 16) & 1u);
    return (unsigned short)(r >> 16);
}
static __device__ __forceinline__ float bf16_to_f(unsigned short s) {
    return __uint_as_float(((unsigned)s) << 16);
}

// ---------------- CSR build ----------------
__global__ void k_count(const int* __restrict__ dst, int E, int* __restrict__ cnt) {
    int e = blockIdx.x * blockDim.x + threadIdx.x;
    if (e < E) atomicAdd(&cnt[dst[e]], 1);
}

__global__ void k_block_sum(const int* __restrict__ cnt, int n, int* __restrict__ bsum) {
    __shared__ int s[256];
    int i = blockIdx.x * 256 + threadIdx.x;
    s[threadIdx.x] = (i < n) ? cnt[i] : 0;
    __syncthreads();
    for (int off = 128; off > 0; off >>= 1) {
        if (threadIdx.x < off) s[threadIdx.x] += s[threadIdx.x + off];
        __syncthreads();
    }
    if (threadIdx.x == 0) bsum[blockIdx.x] = s[0];
}

// exclusive scan of block sums; requires nb <= 256 (M <= 65536)
__global__ void k_scan_bsum(const int* __restrict__ bsum, int nb, int* __restrict__ boff) {
    __shared__ int s[256];
    int t = threadIdx.x;
    int v = (t < nb) ? bsum[t] : 0;
    s[t] = v;
    __syncthreads();
    for (int off = 1; off < 256; off <<= 1) {
        int tv = (t >= off) ? s[t - off] : 0;
        __syncthreads();
        s[t] += tv;
        __syncthreads();
    }
    if (t < nb) boff[t] = s[t] - v;
}

__global__ void k_scan_block(const int* __restrict__ cnt, int n,
                             const int* __restrict__ boff, int* __restrict__ rowptr) {
    __shared__ int s[256];
    int i = blockIdx.x * 256 + threadIdx.x;
    int v = (i < n) ? cnt[i] : 0;
    s[threadIdx.x] = v;
    __syncthreads();
    for (int off = 1; off < 256; off <<= 1) {
        int tv = (threadIdx.x >= off) ? s[threadIdx.x - off] : 0;
        __syncthreads();
        s[threadIdx.x] += tv;
        __syncthreads();
    }
    if (i < n) rowptr[i] = boff[blockIdx.x] + s[threadIdx.x] - v;
    if (i == n - 1) rowptr[n] = boff[blockIdx.x] + s[threadIdx.x];
}

__global__ void k_fill(const int* __restrict__ src, const int* __restrict__ dst, int E,
                       const int* __restrict__ rowptr, int* __restrict__ fillc,
                       int* __restrict__ esrc) {
    int e = blockIdx.x * blockDim.x + threadIdx.x;
    if (e < E) {
        int d = dst[e];
        int pos = rowptr[d] + atomicAdd(&fillc[d], 1);
        esrc[pos] = src[e];
    }
}

__global__ void k_dinv(const int* __restrict__ cnt, int n, float* __restrict__ dinv) {
    int i = blockIdx.x * blockDim.x + threadIdx.x;
    if (i < n) dinv[i] = rsqrtf((float)(cnt[i] + 1));   // +1 self-loop
}

__global__ void k_gcnt(const int* __restrict__ batch, int n, int* __restrict__ gcnt) {
    int i = blockIdx.x * blockDim.x + threadIdx.x;
    if (i < n) atomicAdd(&gcnt[batch[i]], 1);
}

// ---------------- W prep: split fp32 W[K][N] into bf16 hi/lo, TRANSPOSED to [N][K] ----
// [N][K] layout makes the MFMA B-fragment (fixed col, 8 contiguous k) a 16B load.
__global__ void k_wsplit(const float* __restrict__ W,
                         unsigned short* __restrict__ Wt_hi,
                         unsigned short* __restrict__ Wt_lo) {
    const int k = blockIdx.x;    // 256
    const int n = threadIdx.x;   // 256
    const float w = W[k * FEAT + n];
    const unsigned short hi = bf16_rne(w);
    const unsigned short lo = bf16_rne(w - bf16_to_f(hi));
    Wt_hi[n * FEAT + k] = hi;
    Wt_lo[n * FEAT + k] = lo;
}

// ---------------- MFMA GEMM: C[M x 256] = op(A) @ W, row-scaled by dinv -------------
// op(A) = USEBN ? relu(A*scale[k]+shift[k]) : A  (prev layer's BN+ReLU fused)
// Split precision: a = a_hi + a_lo (bf16 each); C = Ah*Bh + Ah*Bl + Al*Bh  (~2e-5 rel err)
// Block: 256 thr = 4 waves; tile 64(M) x 256(N); wave w owns cols [w*64, w*64+64).
// MFMA 16x16x32_bf16 fragment maps (m89-verified C/D): A: row=l&15, k=(l>>4)*8+j;
// B: col=l&15, k=(l>>4)*8+j;  D: col=l&15, row=(l>>4)*4+reg.
// Requires M % 64 == 0 (M=40000 -> 625 blocks, exact).
template <int USEBN>
__global__ __launch_bounds__(256) void k_gemm_mfma(
    const float* __restrict__ A,
    const unsigned short* __restrict__ Bt_hi,   // [N=256][K=256] bf16
    const unsigned short* __restrict__ Bt_lo,
    const float* __restrict__ scale, const float* __restrict__ shift,
    const float* __restrict__ dinv, float* __restrict__ C)
{
    const int t    = threadIdx.x;
    const int wave = t >> 6;
    const int l    = t & 63;
    const int l15  = l & 15;
    const int lg   = l >> 4;              // k-group (loads) / row-group (stores)
    const int tm   = blockIdx.x * 64;
    const int tn   = wave * 64;

    f32x4 acc[4][4];
#pragma unroll
    for (int fm = 0; fm < 4; ++fm)
#pragma unroll
        for (int fn = 0; fn < 4; ++fn) {
            acc[fm][fn][0] = 0.f; acc[fm][fn][1] = 0.f;
            acc[fm][fn][2] = 0.f; acc[fm][fn][3] = 0.f;
        }

#pragma unroll 2
    for (int ks = 0; ks < 8; ++ks) {
        const int kb = ks * 32 + lg * 8;              // this lane's k-run base

        float scv[8], shv[8];
        if (USEBN) {
            *(float4*)&scv[0] = *(const float4*)(scale + kb);
            *(float4*)&scv[4] = *(const float4*)(scale + kb + 4);
            *(float4*)&shv[0] = *(const float4*)(shift + kb);
            *(float4*)&shv[4] = *(const float4*)(shift + kb + 4);
        }

        // A fragments: load fp32, apply op, split hi/lo in-register
        short8v ah[4], al[4];
#pragma unroll
        for (int fm = 0; fm < 4; ++fm) {
            const float* ap = A + (size_t)(tm + fm * 16 + l15) * FEAT + kb;
            float av[8];
            *(float4*)&av[0] = *(const float4*)ap;
            *(float4*)&av[4] = *(const float4*)(ap + 4);
#pragma unroll
            for (int j = 0; j < 8; ++j) {
                float a = av[j];
                if (USEBN) a = frelu(a * scv[j] + shv[j]);
                const unsigned short hi = bf16_rne(a);
                ah[fm][j] = (short)hi;
                al[fm][j] = (short)bf16_rne(a - bf16_to_f(hi));
            }
        }

        // B fragments: pre-split bf16, contiguous 16B loads
        short8v bh[4], bl[4];
#pragma unroll
        for (int fn = 0; fn < 4; ++fn) {
            const size_t bo = (size_t)(tn + fn * 16 + l15) * FEAT + kb;
            bh[fn] = *(const short8v*)(Bt_hi + bo);
            bl[fn] = *(const short8v*)(Bt_lo + bo);
        }

#pragma unroll
        for (int fm = 0; fm < 4; ++fm)
#pragma unroll
            for (int fn = 0; fn < 4; ++fn) {
                acc[fm][fn] = __builtin_amdgcn_mfma_f32_16x16x32_bf16(
                    ah[fm], bh[fn], acc[fm][fn], 0, 0, 0);
                acc[fm][fn] = __builtin_amdgcn_mfma_f32_16x16x32_bf16(
                    ah[fm], bl[fn], acc[fm][fn], 0, 0, 0);
                acc[fm][fn] = __builtin_amdgcn_mfma_f32_16x16x32_bf16(
                    al[fm], bh[fn], acc[fm][fn], 0, 0, 0);
            }
    }

    // epilogue: D row=(l>>4)*4+reg, col=l&15; scale by dinv[row]
#pragma unroll
    for (int fm = 0; fm < 4; ++fm)
#pragma unroll
        for (int r = 0; r < 4; ++r) {
            const int row = tm + fm * 16 + lg * 4 + r;
            const float dv = dinv[row];
            float* cp = C + (size_t)row * FEAT + tn + l15;
#pragma unroll
            for (int fn = 0; fn < 4; ++fn)
                cp[fn * 16] = acc[fm][fn][r] * dv;
        }
}

// ---------------- CSR aggregation: out[v] = dinv[v]*(hs[v] + sum_in hs[u]) + b ------
__global__ __launch_bounds__(256) void k_agg(
    const float* __restrict__ hs, const int* __restrict__ rowptr,
    const int* __restrict__ esrc, const float* __restrict__ dinv,
    const float* __restrict__ bias, float* __restrict__ out, int M)
{
    const int wave = threadIdx.x >> 6;
    const int lane = threadIdx.x & 63;
    const int v = blockIdx.x * 4 + wave;
    if (v >= M) return;
    float4 acc = ((const float4*)(hs + (size_t)v * FEAT))[lane];   // self-loop term
    const int e0 = rowptr[v], e1 = rowptr[v + 1];
    for (int e = e0; e < e1; ++e) {
        const int u = esrc[e];
        const float4 m = ((const float4*)(hs + (size_t)u * FEAT))[lane];
        acc.x += m.x; acc.y += m.y; acc.z += m.z; acc.w += m.w;
    }
    const float dv = dinv[v];
    const float4 bb = ((const float4*)bias)[lane];
    float4 o;
    o.x = acc.x * dv + bb.x;  o.y = acc.y * dv + bb.y;
    o.z = acc.z * dv + bb.z;  o.w = acc.w * dv + bb.w;
    ((float4*)(out + (size_t)v * FEAT))[lane] = o;
}

// ---------------- BN stats ----------------
__global__ void k_stats(const float* __restrict__ x, int M,
                        float* __restrict__ sum, float* __restrict__ sumsq) {
    const int c = threadIdx.x;
    float s = 0.f, q = 0.f;
    for (int r = blockIdx.x; r < M; r += gridDim.x) {
        const float v = x[(size_t)r * FEAT + c];
        s += v; q += v * v;
    }
    atomicAdd(&sum[c], s);
    atomicAdd(&sumsq[c], q);
}

__global__ void k_bnparams(const float* __restrict__ sum, const float* __restrict__ sumsq,
                           const float* __restrict__ gamma, const float* __restrict__ beta,
                           int M, float* __restrict__ scale, float* __restrict__ shift) {
    const int c = threadIdx.x;
    const float mu = sum[c] / (float)M;
    const float var = sumsq[c] / (float)M - mu * mu;
    const float rstd = rsqrtf(var + BN_EPS);
    const float sc = gamma[c] * rstd;
    scale[c] = sc;
    shift[c] = beta[c] - mu * sc;
}

// ---------------- pooling (batch is sorted): run-length accumulate ----------------
__global__ void k_pool(const float* __restrict__ x, const int* __restrict__ batch,
                       const float* __restrict__ scale, const float* __restrict__ shift,
                       float* __restrict__ pool, int M, int rowsPerBlock) {
    const int c = threadIdx.x;
    int r0 = blockIdx.x * rowsPerBlock;
    int r1 = min(r0 + rowsPerBlock, M);
    if (r0 >= r1) return;
    const float sc = scale[c], sh = shift[c];
    float acc = 0.f;
    int cur = batch[r0];
    for (int r = r0; r < r1; ++r) {
        const int g = batch[r];
        if (g != cur) {
            atomicAdd(&pool[(size_t)cur * FEAT + c], acc);
            acc = 0.f; cur = g;
        }
        acc += frelu(x[(size_t)r * FEAT + c] * sc + sh);
    }
    atomicAdd(&pool[(size_t)cur * FEAT + c], acc);
}

__global__ void k_poolfin(const float* __restrict__ pool, const int* __restrict__ gcnt,
                          float* __restrict__ out) {
    const int g = blockIdx.x, c = threadIdx.x;
    const float cnt = fmaxf((float)gcnt[g], 1.f);
    out[(size_t)g * FEAT + c] = pool[(size_t)g * FEAT + c] / cnt;
}

// ---------------- launch ----------------
extern "C" void kernel_launch(void* const* d_in, const int* in_sizes, int n_in,
                              void* d_out, int out_size, void* d_ws, size_t ws_size,
                              hipStream_t stream) {
    const float* x   = (const float*)d_in[0];
    const int*   ei  = (const int*)d_in[1];
    const int* batch = (const int*)d_in[2];
    const float* W1  = (const float*)d_in[3];
    const float* b1  = (const float*)d_in[4];
    const float* g1  = (const float*)d_in[5];
    const float* be1 = (const float*)d_in[6];
    const float* W2  = (const float*)d_in[7];
    const float* b2  = (const float*)d_in[8];
    const float* g2  = (const float*)d_in[9];
    const float* be2 = (const float*)d_in[10];
    float* out = (float*)d_out;

    const int M = in_sizes[2];          // 40000 nodes (divisible by 64)
    const int E = in_sizes[1] / 2;      // 640000 edges
    const int G = out_size / FEAT;      // 64 graphs
    const int* src_in = ei;
    const int* dst_in = ei + E;

    char* p = (char*)d_ws;
    size_t off = 0;
    auto take = [&](size_t bytes) -> char* {
        char* r = p + off;
        off = (off + bytes + 255) & ~(size_t)255;
        return r;
    };
    float* bufA  = (float*)take((size_t)M * FEAT * 4);
    float* bufB  = (float*)take((size_t)M * FEAT * 4);
    int*   esrc  = (int*)take((size_t)E * 4);
    int*   rowptr= (int*)take((size_t)(M + 1) * 4);
    char*  z0 = p + off;                     // ---- zeroed region start ----
    int*   degcnt= (int*)take((size_t)M * 4);
    int*   fillc = (int*)take((size_t)M * 4);
    float* sum1  = (float*)take(FEAT * 4);
    float* sq1   = (float*)take(FEAT * 4);
    float* sum2  = (float*)take(FEAT * 4);
    float* sq2   = (float*)take(FEAT * 4);
    float* pool  = (float*)take((size_t)G * FEAT * 4);
    int*   gcnt  = (int*)take((size_t)G * 4);
    size_t zbytes = (size_t)((p + off) - z0);  // ---- zeroed region end ----
    float* dinv  = (float*)take((size_t)M * 4);
    float* sc1   = (float*)take(FEAT * 4);
    float* sh1   = (float*)take(FEAT * 4);
    float* sc2   = (float*)take(FEAT * 4);
    float* sh2   = (float*)take(FEAT * 4);
    unsigned short* Wt1h = (unsigned short*)take(FEAT * FEAT * 2);
    unsigned short* Wt1l = (unsigned short*)take(FEAT * FEAT * 2);
    unsigned short* Wt2h = (unsigned short*)take(FEAT * FEAT * 2);
    unsigned short* Wt2l = (unsigned short*)take(FEAT * FEAT * 2);
    const int nb = (M + 255) / 256;
    int* bsum = (int*)take((size_t)nb * 4);
    int* boff = (int*)take((size_t)nb * 4);

    hipMemsetAsync(z0, 0, zbytes, stream);

    const int eb = (E + 255) / 256;
    k_count<<<eb, 256, 0, stream>>>(dst_in, E, degcnt);
    k_block_sum<<<nb, 256, 0, stream>>>(degcnt, M, bsum);
    k_scan_bsum<<<1, 256, 0, stream>>>(bsum, nb, boff);
    k_scan_block<<<nb, 256, 0, stream>>>(degcnt, M, boff, rowptr);
    k_fill<<<eb, 256, 0, stream>>>(src_in, dst_in, E, rowptr, fillc, esrc);
    k_dinv<<<nb, 256, 0, stream>>>(degcnt, M, dinv);
    k_gcnt<<<nb, 256, 0, stream>>>(batch, M, gcnt);
    k_wsplit<<<FEAT, FEAT, 0, stream>>>(W1, Wt1h, Wt1l);
    k_wsplit<<<FEAT, FEAT, 0, stream>>>(W2, Wt2h, Wt2l);

    const int mb = M / 64;   // M=40000 -> 625, exact
    // layer 1
    k_gemm_mfma<0><<<mb, 256, 0, stream>>>(x, Wt1h, Wt1l, nullptr, nullptr, dinv, bufA);
    k_agg<<<(M + 3) / 4, 256, 0, stream>>>(bufA, rowptr, esrc, dinv, b1, bufB, M);
    k_stats<<<256, 256, 0, stream>>>(bufB, M, sum1, sq1);
    k_bnparams<<<1, 256, 0, stream>>>(sum1, sq1, g1, be1, M, sc1, sh1);
    // layer 2 (BN1+ReLU fused into GEMM2's A-load, before the hi/lo split)
    k_gemm_mfma<1><<<mb, 256, 0, stream>>>(bufB, Wt2h, Wt2l, sc1, sh1, dinv, bufA);
    k_agg<<<(M + 3) / 4, 256, 0, stream>>>(bufA, rowptr, esrc, dinv, b2, bufB, M);
    k_stats<<<256, 256, 0, stream>>>(bufB, M, sum2, sq2);
    k_bnparams<<<1, 256, 0, stream>>>(sum2, sq2, g2, be2, M, sc2, sh2);
    // BN2+ReLU fused into pooling
    const int rpb = (M + 159) / 160;
    k_pool<<<160, 256, 0, stream>>>(bufB, batch, sc2, sh2, pool, M, rpb);
    k_poolfin<<<G, 256, 0, stream>>>(pool, gcnt, out);
}

// Round 8
// 606.365 us; speedup vs baseline: 1.3821x; 1.3821x over previous
//
#include <hip/hip_runtime.h>

#define FEAT 256
#define BN_EPS 1e-5f

typedef __attribute__((ext_vector_type(8))) short short8v;  // 8 bf16 = 4 VGPRs
typedef __attribute__((ext_vector_type(4))) float f32x4;    // MFMA C/D

static __device__ __forceinline__ float frelu(float x) { return fmaxf(x, 0.f); }

// bf16 round-to-nearest-even split helpers (manual, no header dependence)
static __device__ __forceinline__ unsigned short bf16_rne(float f) {
    unsigned u = __float_as_uint(f);
    unsigned r = u + 0x7FFFu + ((u >> 16) & 1u);
    return (unsigned short)(r >> 16);
}
static __device__ __forceinline__ float bf16_to_f(unsigned short s) {
    return __uint_as_float(((unsigned)s) << 16);
}

// ---------------- CSR build ----------------
__global__ void k_count(const int* __restrict__ dst, int E, int* __restrict__ cnt) {
    int e = blockIdx.x * blockDim.x + threadIdx.x;
    if (e < E) atomicAdd(&cnt[dst[e]], 1);
}

__global__ void k_block_sum(const int* __restrict__ cnt, int n, int* __restrict__ bsum) {
    __shared__ int s[256];
    int i = blockIdx.x * 256 + threadIdx.x;
    s[threadIdx.x] = (i < n) ? cnt[i] : 0;
    __syncthreads();
    for (int off = 128; off > 0; off >>= 1) {
        if (threadIdx.x < off) s[threadIdx.x] += s[threadIdx.x + off];
        __syncthreads();
    }
    if (threadIdx.x == 0) bsum[blockIdx.x] = s[0];
}

// exclusive scan of block sums; requires nb <= 256 (M <= 65536)
__global__ void k_scan_bsum(const int* __restrict__ bsum, int nb, int* __restrict__ boff) {
    __shared__ int s[256];
    int t = threadIdx.x;
    int v = (t < nb) ? bsum[t] : 0;
    s[t] = v;
    __syncthreads();
    for (int off = 1; off < 256; off <<= 1) {
        int tv = (t >= off) ? s[t - off] : 0;
        __syncthreads();
        s[t] += tv;
        __syncthreads();
    }
    if (t < nb) boff[t] = s[t] - v;
}

__global__ void k_scan_block(const int* __restrict__ cnt, int n,
                             const int* __restrict__ boff, int* __restrict__ rowptr) {
    __shared__ int s[256];
    int i = blockIdx.x * 256 + threadIdx.x;
    int v = (i < n) ? cnt[i] : 0;
    s[threadIdx.x] = v;
    __syncthreads();
    for (int off = 1; off < 256; off <<= 1) {
        int tv = (threadIdx.x >= off) ? s[threadIdx.x - off] : 0;
        __syncthreads();
        s[threadIdx.x] += tv;
        __syncthreads();
    }
    if (i < n) rowptr[i] = boff[blockIdx.x] + s[threadIdx.x] - v;
    if (i == n - 1) rowptr[n] = boff[blockIdx.x] + s[threadIdx.x];
}

__global__ void k_fill(const int* __restrict__ src, const int* __restrict__ dst, int E,
                       const int* __restrict__ rowptr, int* __restrict__ fillc,
                       int* __restrict__ esrc) {
    int e = blockIdx.x * blockDim.x + threadIdx.x;
    if (e < E) {
        int d = dst[e];
        int pos = rowptr[d] + atomicAdd(&fillc[d], 1);
        esrc[pos] = src[e];
    }
}

__global__ void k_dinv(const int* __restrict__ cnt, int n, float* __restrict__ dinv) {
    int i = blockIdx.x * blockDim.x + threadIdx.x;
    if (i < n) dinv[i] = rsqrtf((float)(cnt[i] + 1));   // +1 self-loop
}

// batch is SORTED: gcnt[g] = lower_bound(g+1) - lower_bound(g). Zero atomics.
// (replaces atomic count: 40000 same-line atomics serialized at ~4.7ns = 188us)
__global__ void k_gcnt_bs(const int* __restrict__ batch, int n, int G,
                          int* __restrict__ gcnt) {
    const int g = threadIdx.x;
    if (g >= G) return;
    int lo = 0, hi = n;
    while (lo < hi) { int mid = (lo + hi) >> 1; if (batch[mid] < g) lo = mid + 1; else hi = mid; }
    const int lb = lo;
    lo = 0; hi = n;
    while (lo < hi) { int mid = (lo + hi) >> 1; if (batch[mid] < g + 1) lo = mid + 1; else hi = mid; }
    gcnt[g] = lo - lb;
}

// ---------------- W prep: split fp32 W[K][N] into bf16 hi/lo, TRANSPOSED to [N][K] ----
// [N][K] layout makes the MFMA B-fragment (fixed col, 8 contiguous k) a 16B load.
__global__ void k_wsplit(const float* __restrict__ W,
                         unsigned short* __restrict__ Wt_hi,
                         unsigned short* __restrict__ Wt_lo) {
    const int k = blockIdx.x;    // 256
    const int n = threadIdx.x;   // 256
    const float w = W[k * FEAT + n];
    const unsigned short hi = bf16_rne(w);
    const unsigned short lo = bf16_rne(w - bf16_to_f(hi));
    Wt_hi[n * FEAT + k] = hi;
    Wt_lo[n * FEAT + k] = lo;
}

// ---------------- MFMA GEMM: C[M x 256] = op(A) @ W, row-scaled by dinv -------------
// op(A) = USEBN ? relu(A*scale[k]+shift[k]) : A  (prev layer's BN+ReLU fused)
// Split precision: a = a_hi + a_lo (bf16 each); C = Ah*Bh + Ah*Bl + Al*Bh  (~2e-5 rel err)
// Block: 256 thr = 4 waves; tile 64(M) x 256(N); wave w owns cols [w*64, w*64+64).
// MFMA 16x16x32_bf16 fragment maps (m89-verified C/D): A: row=l&15, k=(l>>4)*8+j;
// B: col=l&15, k=(l>>4)*8+j;  D: col=l&15, row=(l>>4)*4+reg.
// Requires M % 64 == 0 (M=40000 -> 625 blocks, exact).
template <int USEBN>
__global__ __launch_bounds__(256) void k_gemm_mfma(
    const float* __restrict__ A,
    const unsigned short* __restrict__ Bt_hi,   // [N=256][K=256] bf16
    const unsigned short* __restrict__ Bt_lo,
    const float* __restrict__ scale, const float* __restrict__ shift,
    const float* __restrict__ dinv, float* __restrict__ C)
{
    const int t    = threadIdx.x;
    const int wave = t >> 6;
    const int l    = t & 63;
    const int l15  = l & 15;
    const int lg   = l >> 4;              // k-group (loads) / row-group (stores)
    const int tm   = blockIdx.x * 64;
    const int tn   = wave * 64;

    f32x4 acc[4][4];
#pragma unroll
    for (int fm = 0; fm < 4; ++fm)
#pragma unroll
        for (int fn = 0; fn < 4; ++fn) {
            acc[fm][fn][0] = 0.f; acc[fm][fn][1] = 0.f;
            acc[fm][fn][2] = 0.f; acc[fm][fn][3] = 0.f;
        }

#pragma unroll 2
    for (int ks = 0; ks < 8; ++ks) {
        const int kb = ks * 32 + lg * 8;              // this lane's k-run base

        float scv[8], shv[8];
        if (USEBN) {
            *(float4*)&scv[0] = *(const float4*)(scale + kb);
            *(float4*)&scv[4] = *(const float4*)(scale + kb + 4);
            *(float4*)&shv[0] = *(const float4*)(shift + kb);
            *(float4*)&shv[4] = *(const float4*)(shift + kb + 4);
        }

        // A fragments: load fp32, apply op, split hi/lo in-register
        short8v ah[4], al[4];
#pragma unroll
        for (int fm = 0; fm < 4; ++fm) {
            const float* ap = A + (size_t)(tm + fm * 16 + l15) * FEAT + kb;
            float av[8];
            *(float4*)&av[0] = *(const float4*)ap;
            *(float4*)&av[4] = *(const float4*)(ap + 4);
#pragma unroll
            for (int j = 0; j < 8; ++j) {
                float a = av[j];
                if (USEBN) a = frelu(a * scv[j] + shv[j]);
                const unsigned short hi = bf16_rne(a);
                ah[fm][j] = (short)hi;
                al[fm][j] = (short)bf16_rne(a - bf16_to_f(hi));
            }
        }

        // B fragments: pre-split bf16, contiguous 16B loads
        short8v bh[4], bl[4];
#pragma unroll
        for (int fn = 0; fn < 4; ++fn) {
            const size_t bo = (size_t)(tn + fn * 16 + l15) * FEAT + kb;
            bh[fn] = *(const short8v*)(Bt_hi + bo);
            bl[fn] = *(const short8v*)(Bt_lo + bo);
        }

#pragma unroll
        for (int fm = 0; fm < 4; ++fm)
#pragma unroll
            for (int fn = 0; fn < 4; ++fn) {
                acc[fm][fn] = __builtin_amdgcn_mfma_f32_16x16x32_bf16(
                    ah[fm], bh[fn], acc[fm][fn], 0, 0, 0);
                acc[fm][fn] = __builtin_amdgcn_mfma_f32_16x16x32_bf16(
                    ah[fm], bl[fn], acc[fm][fn], 0, 0, 0);
                acc[fm][fn] = __builtin_amdgcn_mfma_f32_16x16x32_bf16(
                    al[fm], bh[fn], acc[fm][fn], 0, 0, 0);
            }
    }

    // epilogue: D row=(l>>4)*4+reg, col=l&15; scale by dinv[row]
#pragma unroll
    for (int fm = 0; fm < 4; ++fm)
#pragma unroll
        for (int r = 0; r < 4; ++r) {
            const int row = tm + fm * 16 + lg * 4 + r;
            const float dv = dinv[row];
            float* cp = C + (size_t)row * FEAT + tn + l15;
#pragma unroll
            for (int fn = 0; fn < 4; ++fn)
                cp[fn * 16] = acc[fm][fn][r] * dv;
        }
}

// ---------------- CSR aggregation: out[v] = dinv[v]*(hs[v] + sum_in hs[u]) + b ------
__global__ __launch_bounds__(256) void k_agg(
    const float* __restrict__ hs, const int* __restrict__ rowptr,
    const int* __restrict__ esrc, const float* __restrict__ dinv,
    const float* __restrict__ bias, float* __restrict__ out, int M)
{
    const int wave = threadIdx.x >> 6;
    const int lane = threadIdx.x & 63;
    const int v = blockIdx.x * 4 + wave;
    if (v >= M) return;
    float4 acc = ((const float4*)(hs + (size_t)v * FEAT))[lane];   // self-loop term
    const int e0 = rowptr[v], e1 = rowptr[v + 1];
    for (int e = e0; e < e1; ++e) {
        const int u = esrc[e];
        const float4 m = ((const float4*)(hs + (size_t)u * FEAT))[lane];
        acc.x += m.x; acc.y += m.y; acc.z += m.z; acc.w += m.w;
    }
    const float dv = dinv[v];
    const float4 bb = ((const float4*)bias)[lane];
    float4 o;
    o.x = acc.x * dv + bb.x;  o.y = acc.y * dv + bb.y;
    o.z = acc.z * dv + bb.z;  o.w = acc.w * dv + bb.w;
    ((float4*)(out + (size_t)v * FEAT))[lane] = o;
}

// ---------------- BN stats ----------------
__global__ void k_stats(const float* __restrict__ x, int M,
                        float* __restrict__ sum, float* __restrict__ sumsq) {
    const int c = threadIdx.x;
    float s = 0.f, q = 0.f;
    for (int r = blockIdx.x; r < M; r += gridDim.x) {
        const float v = x[(size_t)r * FEAT + c];
        s += v; q += v * v;
    }
    atomicAdd(&sum[c], s);
    atomicAdd(&sumsq[c], q);
}

__global__ void k_bnparams(const float* __restrict__ sum, const float* __restrict__ sumsq,
                           const float* __restrict__ gamma, const float* __restrict__ beta,
                           int M, float* __restrict__ scale, float* __restrict__ shift) {
    const int c = threadIdx.x;
    const float mu = sum[c] / (float)M;
    const float var = sumsq[c] / (float)M - mu * mu;
    const float rstd = rsqrtf(var + BN_EPS);
    const float sc = gamma[c] * rstd;
    scale[c] = sc;
    shift[c] = beta[c] - mu * sc;
}

// ---------------- pooling (batch is sorted): run-length accumulate ----------------
__global__ void k_pool(const float* __restrict__ x, const int* __restrict__ batch,
                       const float* __restrict__ scale, const float* __restrict__ shift,
                       float* __restrict__ pool, int M, int rowsPerBlock) {
    const int c = threadIdx.x;
    int r0 = blockIdx.x * rowsPerBlock;
    int r1 = min(r0 + rowsPerBlock, M);
    if (r0 >= r1) return;
    const float sc = scale[c], sh = shift[c];
    float acc = 0.f;
    int cur = batch[r0];
    for (int r = r0; r < r1; ++r) {
        const int g = batch[r];
        if (g != cur) {
            atomicAdd(&pool[(size_t)cur * FEAT + c], acc);
            acc = 0.f; cur = g;
        }
        acc += frelu(x[(size_t)r * FEAT + c] * sc + sh);
    }
    atomicAdd(&pool[(size_t)cur * FEAT + c], acc);
}

__global__ void k_poolfin(const float* __restrict__ pool, const int* __restrict__ gcnt,
                          float* __restrict__ out) {
    const int g = blockIdx.x, c = threadIdx.x;
    const float cnt = fmaxf((float)gcnt[g], 1.f);
    out[(size_t)g * FEAT + c] = pool[(size_t)g * FEAT + c] / cnt;
}

// ---------------- launch ----------------
extern "C" void kernel_launch(void* const* d_in, const int* in_sizes, int n_in,
                              void* d_out, int out_size, void* d_ws, size_t ws_size,
                              hipStream_t stream) {
    const float* x   = (const float*)d_in[0];
    const int*   ei  = (const int*)d_in[1];
    const int* batch = (const int*)d_in[2];
    const float* W1  = (const float*)d_in[3];
    const float* b1  = (const float*)d_in[4];
    const float* g1  = (const float*)d_in[5];
    const float* be1 = (const float*)d_in[6];
    const float* W2  = (const float*)d_in[7];
    const float* b2  = (const float*)d_in[8];
    const float* g2  = (const float*)d_in[9];
    const float* be2 = (const float*)d_in[10];
    float* out = (float*)d_out;

    const int M = in_sizes[2];          // 40000 nodes (divisible by 64)
    const int E = in_sizes[1] / 2;      // 640000 edges
    const int G = out_size / FEAT;      // 64 graphs
    const int* src_in = ei;
    const int* dst_in = ei + E;

    char* p = (char*)d_ws;
    size_t off = 0;
    auto take = [&](size_t bytes) -> char* {
        char* r = p + off;
        off = (off + bytes + 255) & ~(size_t)255;
        return r;
    };
    float* bufA  = (float*)take((size_t)M * FEAT * 4);
    float* bufB  = (float*)take((size_t)M * FEAT * 4);
    int*   esrc  = (int*)take((size_t)E * 4);
    int*   rowptr= (int*)take((size_t)(M + 1) * 4);
    char*  z0 = p + off;                     // ---- zeroed region start ----
    int*   degcnt= (int*)take((size_t)M * 4);
    int*   fillc = (int*)take((size_t)M * 4);
    float* sum1  = (float*)take(FEAT * 4);
    float* sq1   = (float*)take(FEAT * 4);
    float* sum2  = (float*)take(FEAT * 4);
    float* sq2   = (float*)take(FEAT * 4);
    float* pool  = (float*)take((size_t)G * FEAT * 4);
    size_t zbytes = (size_t)((p + off) - z0);  // ---- zeroed region end ----
    int*   gcnt  = (int*)take((size_t)G * 4);
    float* dinv  = (float*)take((size_t)M * 4);
    float* sc1   = (float*)take(FEAT * 4);
    float* sh1   = (float*)take(FEAT * 4);
    float* sc2   = (float*)take(FEAT * 4);
    float* sh2   = (float*)take(FEAT * 4);
    unsigned short* Wt1h = (unsigned short*)take(FEAT * FEAT * 2);
    unsigned short* Wt1l = (unsigned short*)take(FEAT * FEAT * 2);
    unsigned short* Wt2h = (unsigned short*)take(FEAT * FEAT * 2);
    unsigned short* Wt2l = (unsigned short*)take(FEAT * FEAT * 2);
    const int nb = (M + 255) / 256;
    int* bsum = (int*)take((size_t)nb * 4);
    int* boff = (int*)take((size_t)nb * 4);

    hipMemsetAsync(z0, 0, zbytes, stream);

    const int eb = (E + 255) / 256;
    k_count<<<eb, 256, 0, stream>>>(dst_in, E, degcnt);
    k_block_sum<<<nb, 256, 0, stream>>>(degcnt, M, bsum);
    k_scan_bsum<<<1, 256, 0, stream>>>(bsum, nb, boff);
    k_scan_block<<<nb, 256, 0, stream>>>(degcnt, M, boff, rowptr);
    k_fill<<<eb, 256, 0, stream>>>(src_in, dst_in, E, rowptr, fillc, esrc);
    k_dinv<<<nb, 256, 0, stream>>>(degcnt, M, dinv);
    k_gcnt_bs<<<1, 64, 0, stream>>>(batch, M, G, gcnt);
    k_wsplit<<<FEAT, FEAT, 0, stream>>>(W1, Wt1h, Wt1l);
    k_wsplit<<<FEAT, FEAT, 0, stream>>>(W2, Wt2h, Wt2l);

    const int mb = M / 64;   // M=40000 -> 625, exact
    // layer 1
    k_gemm_mfma<0><<<mb, 256, 0, stream>>>(x, Wt1h, Wt1l, nullptr, nullptr, dinv, bufA);
    k_agg<<<(M + 3) / 4, 256, 0, stream>>>(bufA, rowptr, esrc, dinv, b1, bufB, M);
    k_stats<<<256, 256, 0, stream>>>(bufB, M, sum1, sq1);
    k_bnparams<<<1, 256, 0, stream>>>(sum1, sq1, g1, be1, M, sc1, sh1);
    // layer 2 (BN1+ReLU fused into GEMM2's A-load, before the hi/lo split)
    k_gemm_mfma<1><<<mb, 256, 0, stream>>>(bufB, Wt2h, Wt2l, sc1, sh1, dinv, bufA);
    k_agg<<<(M + 3) / 4, 256, 0, stream>>>(bufA, rowptr, esrc, dinv, b2, bufB, M);
    k_stats<<<256, 256, 0, stream>>>(bufB, M, sum2, sq2);
    k_bnparams<<<1, 256, 0, stream>>>(sum2, sq2, g2, be2, M, sc2, sh2);
    // BN2+ReLU fused into pooling (1024 blocks: 4/CU occupancy for the 41MB read)
    const int pblocks = 1024;
    const int rpb = (M + pblocks - 1) / pblocks;
    k_pool<<<pblocks, 256, 0, stream>>>(bufB, batch, sc2, sh2, pool, M, rpb);
    k_poolfin<<<G, 256, 0, stream>>>(pool, gcnt, out);
}

// Round 12
// 602.371 us; speedup vs baseline: 1.3913x; 1.0066x over previous
//
#include <hip/hip_runtime.h>

#define FEAT 256
#define BN_EPS 1e-5f

typedef __attribute__((ext_vector_type(8))) short short8v;  // 8 bf16 = 4 VGPRs
typedef __attribute__((ext_vector_type(4))) float f32x4;    // MFMA C/D

static __device__ __forceinline__ float frelu(float x) { return fmaxf(x, 0.f); }

// bf16 round-to-nearest-even split helpers (manual, no header dependence)
static __device__ __forceinline__ unsigned short bf16_rne(float f) {
    unsigned u = __float_as_uint(f);
    unsigned r = u + 0x7FFFu + ((u >> 16) & 1u);
    return (unsigned short)(r >> 16);
}
static __device__ __forceinline__ float bf16_to_f(unsigned short s) {
    return __uint_as_float(((unsigned)s) << 16);
}

// ---------------- CSR build ----------------
__global__ void k_count(const int* __restrict__ dst, int E, int* __restrict__ cnt) {
    int e = blockIdx.x * blockDim.x + threadIdx.x;
    if (e < E) atomicAdd(&cnt[dst[e]], 1);
}

__global__ void k_block_sum(const int* __restrict__ cnt, int n, int* __restrict__ bsum) {
    __shared__ int s[256];
    int i = blockIdx.x * 256 + threadIdx.x;
    s[threadIdx.x] = (i < n) ? cnt[i] : 0;
    __syncthreads();
    for (int off = 128; off > 0; off >>= 1) {
        if (threadIdx.x < off) s[threadIdx.x] += s[threadIdx.x + off];
        __syncthreads();
    }
    if (threadIdx.x == 0) bsum[blockIdx.x] = s[0];
}

// exclusive scan of block sums; requires nb <= 256 (M <= 65536)
__global__ void k_scan_bsum(const int* __restrict__ bsum, int nb, int* __restrict__ boff) {
    __shared__ int s[256];
    int t = threadIdx.x;
    int v = (t < nb) ? bsum[t] : 0;
    s[t] = v;
    __syncthreads();
    for (int off = 1; off < 256; off <<= 1) {
        int tv = (t >= off) ? s[t - off] : 0;
        __syncthreads();
        s[t] += tv;
        __syncthreads();
    }
    if (t < nb) boff[t] = s[t] - v;
}

__global__ void k_scan_block(const int* __restrict__ cnt, int n,
                             const int* __restrict__ boff, int* __restrict__ rowptr) {
    __shared__ int s[256];
    int i = blockIdx.x * 256 + threadIdx.x;
    int v = (i < n) ? cnt[i] : 0;
    s[threadIdx.x] = v;
    __syncthreads();
    for (int off = 1; off < 256; off <<= 1) {
        int tv = (threadIdx.x >= off) ? s[threadIdx.x - off] : 0;
        __syncthreads();
        s[threadIdx.x] += tv;
        __syncthreads();
    }
    if (i < n) rowptr[i] = boff[blockIdx.x] + s[threadIdx.x] - v;
    if (i == n - 1) rowptr[n] = boff[blockIdx.x] + s[threadIdx.x];
}

__global__ void k_fill(const int* __restrict__ src, const int* __restrict__ dst, int E,
                       const int* __restrict__ rowptr, int* __restrict__ fillc,
                       int* __restrict__ esrc) {
    int e = blockIdx.x * blockDim.x + threadIdx.x;
    if (e < E) {
        int d = dst[e];
        int pos = rowptr[d] + atomicAdd(&fillc[d], 1);
        esrc[pos] = src[e];
    }
}

__global__ void k_dinv(const int* __restrict__ cnt, int n, float* __restrict__ dinv) {
    int i = blockIdx.x * blockDim.x + threadIdx.x;
    if (i < n) dinv[i] = rsqrtf((float)(cnt[i] + 1));   // +1 self-loop
}

// batch is SORTED: gcnt[g] = lower_bound(g+1) - lower_bound(g). Zero atomics.
// (replaces atomic count: 40000 same-line atomics serialized at ~4.7ns = 188us)
__global__ void k_gcnt_bs(const int* __restrict__ batch, int n, int G,
                          int* __restrict__ gcnt) {
    const int g = threadIdx.x;
    if (g >= G) return;
    int lo = 0, hi = n;
    while (lo < hi) { int mid = (lo + hi) >> 1; if (batch[mid] < g) lo = mid + 1; else hi = mid; }
    const int lb = lo;
    lo = 0; hi = n;
    while (lo < hi) { int mid = (lo + hi) >> 1; if (batch[mid] < g + 1) lo = mid + 1; else hi = mid; }
    gcnt[g] = lo - lb;
}

// ---------------- W prep: split fp32 W[K][N] into bf16 hi/lo, TRANSPOSED to [N][K] ----
// [N][K] layout makes the MFMA B-fragment (fixed col, 8 contiguous k) a 16B load.
__global__ void k_wsplit(const float* __restrict__ W,
                         unsigned short* __restrict__ Wt_hi,
                         unsigned short* __restrict__ Wt_lo) {
    const int k = blockIdx.x;    // 256
    const int n = threadIdx.x;   // 256
    const float w = W[k * FEAT + n];
    const unsigned short hi = bf16_rne(w);
    const unsigned short lo = bf16_rne(w - bf16_to_f(hi));
    Wt_hi[n * FEAT + k] = hi;
    Wt_lo[n * FEAT + k] = lo;
}

// ---------------- MFMA GEMM: C[M x 256] = op(A) @ W, row-scaled by dinv -------------
// op(A) = USEBN ? relu(A*scale[k]+shift[k]) : A  (prev layer's BN+ReLU fused)
// Split precision: a = a_hi + a_lo (bf16 each); C = Ah*Bh + Ah*Bl + Al*Bh  (~2e-5 rel err)
// Block: 256 thr = 4 waves; tile 64(M) x 256(N); wave w owns cols [w*64, w*64+64).
// MFMA 16x16x32_bf16 fragment maps (m89-verified C/D): A: row=l&15, k=(l>>4)*8+j;
// B: col=l&15, k=(l>>4)*8+j;  D: col=l&15, row=(l>>4)*4+reg.
// Requires M % 64 == 0 (M=40000 -> 625 blocks, exact).
template <int USEBN>
__global__ __launch_bounds__(256) void k_gemm_mfma(
    const float* __restrict__ A,
    const unsigned short* __restrict__ Bt_hi,   // [N=256][K=256] bf16
    const unsigned short* __restrict__ Bt_lo,
    const float* __restrict__ scale, const float* __restrict__ shift,
    const float* __restrict__ dinv, float* __restrict__ C)
{
    const int t    = threadIdx.x;
    const int wave = t >> 6;
    const int l    = t & 63;
    const int l15  = l & 15;
    const int lg   = l >> 4;              // k-group (loads) / row-group (stores)
    const int tm   = blockIdx.x * 64;
    const int tn   = wave * 64;

    f32x4 acc[4][4];
#pragma unroll
    for (int fm = 0; fm < 4; ++fm)
#pragma unroll
        for (int fn = 0; fn < 4; ++fn) {
            acc[fm][fn][0] = 0.f; acc[fm][fn][1] = 0.f;
            acc[fm][fn][2] = 0.f; acc[fm][fn][3] = 0.f;
        }

#pragma unroll 2
    for (int ks = 0; ks < 8; ++ks) {
        const int kb = ks * 32 + lg * 8;              // this lane's k-run base

        float scv[8], shv[8];
        if (USEBN) {
            *(float4*)&scv[0] = *(const float4*)(scale + kb);
            *(float4*)&scv[4] = *(const float4*)(scale + kb + 4);
            *(float4*)&shv[0] = *(const float4*)(shift + kb);
            *(float4*)&shv[4] = *(const float4*)(shift + kb + 4);
        }

        // A fragments: load fp32, apply op, split hi/lo in-register
        short8v ah[4], al[4];
#pragma unroll
        for (int fm = 0; fm < 4; ++fm) {
            const float* ap = A + (size_t)(tm + fm * 16 + l15) * FEAT + kb;
            float av[8];
            *(float4*)&av[0] = *(const float4*)ap;
            *(float4*)&av[4] = *(const float4*)(ap + 4);
#pragma unroll
            for (int j = 0; j < 8; ++j) {
                float a = av[j];
                if (USEBN) a = frelu(a * scv[j] + shv[j]);
                const unsigned short hi = bf16_rne(a);
                ah[fm][j] = (short)hi;
                al[fm][j] = (short)bf16_rne(a - bf16_to_f(hi));
            }
        }

        // B fragments: pre-split bf16, contiguous 16B loads
        short8v bh[4], bl[4];
#pragma unroll
        for (int fn = 0; fn < 4; ++fn) {
            const size_t bo = (size_t)(tn + fn * 16 + l15) * FEAT + kb;
            bh[fn] = *(const short8v*)(Bt_hi + bo);
            bl[fn] = *(const short8v*)(Bt_lo + bo);
        }

#pragma unroll
        for (int fm = 0; fm < 4; ++fm)
#pragma unroll
            for (int fn = 0; fn < 4; ++fn) {
                acc[fm][fn] = __builtin_amdgcn_mfma_f32_16x16x32_bf16(
                    ah[fm], bh[fn], acc[fm][fn], 0, 0, 0);
                acc[fm][fn] = __builtin_amdgcn_mfma_f32_16x16x32_bf16(
                    ah[fm], bl[fn], acc[fm][fn], 0, 0, 0);
                acc[fm][fn] = __builtin_amdgcn_mfma_f32_16x16x32_bf16(
                    al[fm], bh[fn], acc[fm][fn], 0, 0, 0);
            }
    }

    // epilogue: D row=(l>>4)*4+reg, col=l&15; scale by dinv[row]
#pragma unroll
    for (int fm = 0; fm < 4; ++fm)
#pragma unroll
        for (int r = 0; r < 4; ++r) {
            const int row = tm + fm * 16 + lg * 4 + r;
            const float dv = dinv[row];
            float* cp = C + (size_t)row * FEAT + tn + l15;
#pragma unroll
            for (int fn = 0; fn < 4; ++fn)
                cp[fn * 16] = acc[fm][fn][r] * dv;
        }
}

// ---------------- CSR aggregation: out[v] = dinv[v]*(hs[v] + sum_in hs[u]) + b ------
// one wave per node; 4-way edge unroll -> 4 independent 1KB gathers in flight (MLP).
// (r8 profile: 9.6% VALUBusy, 46% HBM, 70% occ => latency-bound single gather chain)
__global__ __launch_bounds__(256) void k_agg(
    const float* __restrict__ hs, const int* __restrict__ rowptr,
    const int* __restrict__ esrc, const float* __restrict__ dinv,
    const float* __restrict__ bias, float* __restrict__ out, int M)
{
    const int wave = threadIdx.x >> 6;
    const int lane = threadIdx.x & 63;
    const int v = blockIdx.x * 4 + wave;
    if (v >= M) return;
    const float4* __restrict__ hv = (const float4*)hs;
    float4 a0 = hv[(size_t)v * 64 + lane];                 // self-loop term
    float4 a1 = {0.f, 0.f, 0.f, 0.f};
    float4 a2 = {0.f, 0.f, 0.f, 0.f};
    float4 a3 = {0.f, 0.f, 0.f, 0.f};
    const int e0 = rowptr[v], e1 = rowptr[v + 1];
    int e = e0;
    for (; e + 4 <= e1; e += 4) {
        const int u0 = esrc[e + 0];
        const int u1 = esrc[e + 1];
        const int u2 = esrc[e + 2];
        const int u3 = esrc[e + 3];
        const float4 m0 = hv[(size_t)u0 * 64 + lane];
        const float4 m1 = hv[(size_t)u1 * 64 + lane];
        const float4 m2 = hv[(size_t)u2 * 64 + lane];
        const float4 m3 = hv[(size_t)u3 * 64 + lane];
        a0.x += m0.x; a0.y += m0.y; a0.z += m0.z; a0.w += m0.w;
        a1.x += m1.x; a1.y += m1.y; a1.z += m1.z; a1.w += m1.w;
        a2.x += m2.x; a2.y += m2.y; a2.z += m2.z; a2.w += m2.w;
        a3.x += m3.x; a3.y += m3.y; a3.z += m3.z; a3.w += m3.w;
    }
    if (e + 2 <= e1) {
        const int u0 = esrc[e + 0];
        const int u1 = esrc[e + 1];
        const float4 m0 = hv[(size_t)u0 * 64 + lane];
        const float4 m1 = hv[(size_t)u1 * 64 + lane];
        a1.x += m0.x; a1.y += m0.y; a1.z += m0.z; a1.w += m0.w;
        a2.x += m1.x; a2.y += m1.y; a2.z += m1.z; a2.w += m1.w;
        e += 2;
    }
    if (e < e1) {
        const float4 m0 = hv[(size_t)esrc[e] * 64 + lane];
        a3.x += m0.x; a3.y += m0.y; a3.z += m0.z; a3.w += m0.w;
    }
    const float dv = dinv[v];
    const float4 bb = ((const float4*)bias)[lane];
    float4 o;
    o.x = (a0.x + a1.x + a2.x + a3.x) * dv + bb.x;
    o.y = (a0.y + a1.y + a2.y + a3.y) * dv + bb.y;
    o.z = (a0.z + a1.z + a2.z + a3.z) * dv + bb.z;
    o.w = (a0.w + a1.w + a2.w + a3.w) * dv + bb.w;
    ((float4*)(out + (size_t)v * FEAT))[lane] = o;
}

// ---------------- BN stats ----------------
__global__ void k_stats(const float* __restrict__ x, int M,
                        float* __restrict__ sum, float* __restrict__ sumsq) {
    const int c = threadIdx.x;
    float s = 0.f, q = 0.f;
    for (int r = blockIdx.x; r < M; r += gridDim.x) {
        const float v = x[(size_t)r * FEAT + c];
        s += v; q += v * v;
    }
    atomicAdd(&sum[c], s);
    atomicAdd(&sumsq[c], q);
}

__global__ void k_bnparams(const float* __restrict__ sum, const float* __restrict__ sumsq,
                           const float* __restrict__ gamma, const float* __restrict__ beta,
                           int M, float* __restrict__ scale, float* __restrict__ shift) {
    const int c = threadIdx.x;
    const float mu = sum[c] / (float)M;
    const float var = sumsq[c] / (float)M - mu * mu;
    const float rstd = rsqrtf(var + BN_EPS);
    const float sc = gamma[c] * rstd;
    scale[c] = sc;
    shift[c] = beta[c] - mu * sc;
}

// ---------------- pooling (batch is sorted): run-length accumulate ----------------
__global__ void k_pool(const float* __restrict__ x, const int* __restrict__ batch,
                       const float* __restrict__ scale, const float* __restrict__ shift,
                       float* __restrict__ pool, int M, int rowsPerBlock) {
    const int c = threadIdx.x;
    int r0 = blockIdx.x * rowsPerBlock;
    int r1 = min(r0 + rowsPerBlock, M);
    if (r0 >= r1) return;
    const float sc = scale[c], sh = shift[c];
    float acc = 0.f;
    int cur = batch[r0];
    for (int r = r0; r < r1; ++r) {
        const int g = batch[r];
        if (g != cur) {
            atomicAdd(&pool[(size_t)cur * FEAT + c], acc);
            acc = 0.f; cur = g;
        }
        acc += frelu(x[(size_t)r * FEAT + c] * sc + sh);
    }
    atomicAdd(&pool[(size_t)cur * FEAT + c], acc);
}

__global__ void k_poolfin(const float* __restrict__ pool, const int* __restrict__ gcnt,
                          float* __restrict__ out) {
    const int g = blockIdx.x, c = threadIdx.x;
    const float cnt = fmaxf((float)gcnt[g], 1.f);
    out[(size_t)g * FEAT + c] = pool[(size_t)g * FEAT + c] / cnt;
}

// ---------------- launch ----------------
extern "C" void kernel_launch(void* const* d_in, const int* in_sizes, int n_in,
                              void* d_out, int out_size, void* d_ws, size_t ws_size,
                              hipStream_t stream) {
    const float* x   = (const float*)d_in[0];
    const int*   ei  = (const int*)d_in[1];
    const int* batch = (const int*)d_in[2];
    const float* W1  = (const float*)d_in[3];
    const float* b1  = (const float*)d_in[4];
    const float* g1  = (const float*)d_in[5];
    const float* be1 = (const float*)d_in[6];
    const float* W2  = (const float*)d_in[7];
    const float* b2  = (const float*)d_in[8];
    const float* g2  = (const float*)d_in[9];
    const float* be2 = (const float*)d_in[10];
    float* out = (float*)d_out;

    const int M = in_sizes[2];          // 40000 nodes (divisible by 64)
    const int E = in_sizes[1] / 2;      // 640000 edges
    const int G = out_size / FEAT;      // 64 graphs
    const int* src_in = ei;
    const int* dst_in = ei + E;

    char* p = (char*)d_ws;
    size_t off = 0;
    auto take = [&](size_t bytes) -> char* {
        char* r = p + off;
        off = (off + bytes + 255) & ~(size_t)255;
        return r;
    };
    float* bufA  = (float*)take((size_t)M * FEAT * 4);
    float* bufB  = (float*)take((size_t)M * FEAT * 4);
    int*   esrc  = (int*)take((size_t)E * 4);
    int*   rowptr= (int*)take((size_t)(M + 1) * 4);
    char*  z0 = p + off;                     // ---- zeroed region start ----
    int*   degcnt= (int*)take((size_t)M * 4);
    int*   fillc = (int*)take((size_t)M * 4);
    float* sum1  = (float*)take(FEAT * 4);
    float* sq1   = (float*)take(FEAT * 4);
    float* sum2  = (float*)take(FEAT * 4);
    float* sq2   = (float*)take(FEAT * 4);
    float* pool  = (float*)take((size_t)G * FEAT * 4);
    size_t zbytes = (size_t)((p + off) - z0);  // ---- zeroed region end ----
    int*   gcnt  = (int*)take((size_t)G * 4);
    float* dinv  = (float*)take((size_t)M * 4);
    float* sc1   = (float*)take(FEAT * 4);
    float* sh1   = (float*)take(FEAT * 4);
    float* sc2   = (float*)take(FEAT * 4);
    float* sh2   = (float*)take(FEAT * 4);
    unsigned short* Wt1h = (unsigned short*)take(FEAT * FEAT * 2);
    unsigned short* Wt1l = (unsigned short*)take(FEAT * FEAT * 2);
    unsigned short* Wt2h = (unsigned short*)take(FEAT * FEAT * 2);
    unsigned short* Wt2l = (unsigned short*)take(FEAT * FEAT * 2);
    const int nb = (M + 255) / 256;
    int* bsum = (int*)take((size_t)nb * 4);
    int* boff = (int*)take((size_t)nb * 4);

    hipMemsetAsync(z0, 0, zbytes, stream);

    const int eb = (E + 255) / 256;
    k_count<<<eb, 256, 0, stream>>>(dst_in, E, degcnt);
    k_block_sum<<<nb, 256, 0, stream>>>(degcnt, M, bsum);
    k_scan_bsum<<<1, 256, 0, stream>>>(bsum, nb, boff);
    k_scan_block<<<nb, 256, 0, stream>>>(degcnt, M, boff, rowptr);
    k_fill<<<eb, 256, 0, stream>>>(src_in, dst_in, E, rowptr, fillc, esrc);
    k_dinv<<<nb, 256, 0, stream>>>(degcnt, M, dinv);
    k_gcnt_bs<<<1, 64, 0, stream>>>(batch, M, G, gcnt);
    k_wsplit<<<FEAT, FEAT, 0, stream>>>(W1, Wt1h, Wt1l);
    k_wsplit<<<FEAT, FEAT, 0, stream>>>(W2, Wt2h, Wt2l);

    const int mb = M / 64;   // M=40000 -> 625, exact
    // layer 1
    k_gemm_mfma<0><<<mb, 256, 0, stream>>>(x, Wt1h, Wt1l, nullptr, nullptr, dinv, bufA);
    k_agg<<<(M + 3) / 4, 256, 0, stream>>>(bufA, rowptr, esrc, dinv, b1, bufB, M);
    k_stats<<<256, 256, 0, stream>>>(bufB, M, sum1, sq1);
    k_bnparams<<<1, 256, 0, stream>>>(sum1, sq1, g1, be1, M, sc1, sh1);
    // layer 2 (BN1+ReLU fused into GEMM2's A-load, before the hi/lo split)
    k_gemm_mfma<1><<<mb, 256, 0, stream>>>(bufB, Wt2h, Wt2l, sc1, sh1, dinv, bufA);
    k_agg<<<(M + 3) / 4, 256, 0, stream>>>(bufA, rowptr, esrc, dinv, b2, bufB, M);
    k_stats<<<256, 256, 0, stream>>>(bufB, M, sum2, sq2);
    k_bnparams<<<1, 256, 0, stream>>>(sum2, sq2, g2, be2, M, sc2, sh2);
    // BN2+ReLU fused into pooling (1024 blocks: 4/CU occupancy for the 41MB read)
    const int pblocks = 1024;
    const int rpb = (M + pblocks - 1) / pblocks;
    k_pool<<<pblocks, 256, 0, stream>>>(bufB, batch, sc2, sh2, pool, M, rpb);
    k_poolfin<<<G, 256, 0, stream>>>(pool, gcnt, out);
}

// Round 13
// 497.062 us; speedup vs baseline: 1.6861x; 1.2119x over previous
//
#include <hip/hip_runtime.h>

#define FEAT 256
#define BN_EPS 1e-5f

typedef __attribute__((ext_vector_type(8))) short short8v;    // 8 bf16 = 4 VGPRs
typedef __attribute__((ext_vector_type(4))) float f32x4;      // MFMA C/D
typedef __attribute__((ext_vector_type(4))) _Float16 h16x4;   // 4 fp16 = 8B

static __device__ __forceinline__ float frelu(float x) { return fmaxf(x, 0.f); }

// bf16 round-to-nearest-even split helpers (manual, no header dependence)
static __device__ __forceinline__ unsigned short bf16_rne(float f) {
    unsigned u = __float_as_uint(f);
    unsigned r = u + 0x7FFFu + ((u >> 16) & 1u);
    return (unsigned short)(r >> 16);
}
static __device__ __forceinline__ float bf16_to_f(unsigned short s) {
    return __uint_as_float(((unsigned)s) << 16);
}

// ---------------- CSR build ----------------
__global__ void k_count(const int* __restrict__ dst, int E, int* __restrict__ cnt) {
    int e = blockIdx.x * blockDim.x + threadIdx.x;
    if (e < E) atomicAdd(&cnt[dst[e]], 1);
}

__global__ void k_block_sum(const int* __restrict__ cnt, int n, int* __restrict__ bsum) {
    __shared__ int s[256];
    int i = blockIdx.x * 256 + threadIdx.x;
    s[threadIdx.x] = (i < n) ? cnt[i] : 0;
    __syncthreads();
    for (int off = 128; off > 0; off >>= 1) {
        if (threadIdx.x < off) s[threadIdx.x] += s[threadIdx.x + off];
        __syncthreads();
    }
    if (threadIdx.x == 0) bsum[blockIdx.x] = s[0];
}

// exclusive scan of block sums; requires nb <= 256 (M <= 65536)
__global__ void k_scan_bsum(const int* __restrict__ bsum, int nb, int* __restrict__ boff) {
    __shared__ int s[256];
    int t = threadIdx.x;
    int v = (t < nb) ? bsum[t] : 0;
    s[t] = v;
    __syncthreads();
    for (int off = 1; off < 256; off <<= 1) {
        int tv = (t >= off) ? s[t - off] : 0;
        __syncthreads();
        s[t] += tv;
        __syncthreads();
    }
    if (t < nb) boff[t] = s[t] - v;
}

__global__ void k_scan_block(const int* __restrict__ cnt, int n,
                             const int* __restrict__ boff, int* __restrict__ rowptr) {
    __shared__ int s[256];
    int i = blockIdx.x * 256 + threadIdx.x;
    int v = (i < n) ? cnt[i] : 0;
    s[threadIdx.x] = v;
    __syncthreads();
    for (int off = 1; off < 256; off <<= 1) {
        int tv = (threadIdx.x >= off) ? s[threadIdx.x - off] : 0;
        __syncthreads();
        s[threadIdx.x] += tv;
        __syncthreads();
    }
    if (i < n) rowptr[i] = boff[blockIdx.x] + s[threadIdx.x] - v;
    if (i == n - 1) rowptr[n] = boff[blockIdx.x] + s[threadIdx.x];
}

__global__ void k_fill(const int* __restrict__ src, const int* __restrict__ dst, int E,
                       const int* __restrict__ rowptr, int* __restrict__ fillc,
                       int* __restrict__ esrc) {
    int e = blockIdx.x * blockDim.x + threadIdx.x;
    if (e < E) {
        int d = dst[e];
        int pos = rowptr[d] + atomicAdd(&fillc[d], 1);
        esrc[pos] = src[e];
    }
}

__global__ void k_dinv(const int* __restrict__ cnt, int n, float* __restrict__ dinv) {
    int i = blockIdx.x * blockDim.x + threadIdx.x;
    if (i < n) dinv[i] = rsqrtf((float)(cnt[i] + 1));   // +1 self-loop
}

// batch is SORTED: gcnt[g] = lower_bound(g+1) - lower_bound(g). Zero atomics.
__global__ void k_gcnt_bs(const int* __restrict__ batch, int n, int G,
                          int* __restrict__ gcnt) {
    const int g = threadIdx.x;
    if (g >= G) return;
    int lo = 0, hi = n;
    while (lo < hi) { int mid = (lo + hi) >> 1; if (batch[mid] < g) lo = mid + 1; else hi = mid; }
    const int lb = lo;
    lo = 0; hi = n;
    while (lo < hi) { int mid = (lo + hi) >> 1; if (batch[mid] < g + 1) lo = mid + 1; else hi = mid; }
    gcnt[g] = lo - lb;
}

// ---------------- W prep: split fp32 W[K][N] into bf16 hi/lo, TRANSPOSED to [N][K] ----
__global__ void k_wsplit(const float* __restrict__ W,
                         unsigned short* __restrict__ Wt_hi,
                         unsigned short* __restrict__ Wt_lo) {
    const int k = blockIdx.x;    // 256
    const int n = threadIdx.x;   // 256
    const float w = W[k * FEAT + n];
    const unsigned short hi = bf16_rne(w);
    const unsigned short lo = bf16_rne(w - bf16_to_f(hi));
    Wt_hi[n * FEAT + k] = hi;
    Wt_lo[n * FEAT + k] = lo;
}

// ---------------- MFMA GEMM: C16[M x 256] = fp16( dinv * (op(A) @ W) ) -------------
// op(A) = USEBN ? relu(A*scale[k]+shift[k]) : A  (prev layer's BN+ReLU fused)
// Split precision: a = a_hi + a_lo (bf16 each); C = Ah*Bh + Ah*Bl + Al*Bh  (~2e-5 rel err)
// Output stored fp16 (r12: agg is L2-fill-BW-bound at 320MB fetch; halving gather
// bytes is the lever; fp16 RNE adds ~2^-12 rel — 8x safer than bf16).
template <int USEBN>
__global__ __launch_bounds__(256) void k_gemm_mfma(
    const float* __restrict__ A,
    const unsigned short* __restrict__ Bt_hi,   // [N=256][K=256] bf16
    const unsigned short* __restrict__ Bt_lo,
    const float* __restrict__ scale, const float* __restrict__ shift,
    const float* __restrict__ dinv, _Float16* __restrict__ C16)
{
    const int t    = threadIdx.x;
    const int wave = t >> 6;
    const int l    = t & 63;
    const int l15  = l & 15;
    const int lg   = l >> 4;              // k-group (loads) / row-group (stores)
    const int tm   = blockIdx.x * 64;
    const int tn   = wave * 64;

    f32x4 acc[4][4];
#pragma unroll
    for (int fm = 0; fm < 4; ++fm)
#pragma unroll
        for (int fn = 0; fn < 4; ++fn) {
            acc[fm][fn][0] = 0.f; acc[fm][fn][1] = 0.f;
            acc[fm][fn][2] = 0.f; acc[fm][fn][3] = 0.f;
        }

#pragma unroll 2
    for (int ks = 0; ks < 8; ++ks) {
        const int kb = ks * 32 + lg * 8;              // this lane's k-run base

        float scv[8], shv[8];
        if (USEBN) {
            *(float4*)&scv[0] = *(const float4*)(scale + kb);
            *(float4*)&scv[4] = *(const float4*)(scale + kb + 4);
            *(float4*)&shv[0] = *(const float4*)(shift + kb);
            *(float4*)&shv[4] = *(const float4*)(shift + kb + 4);
        }

        // A fragments: load fp32, apply op, split hi/lo in-register
        short8v ah[4], al[4];
#pragma unroll
        for (int fm = 0; fm < 4; ++fm) {
            const float* ap = A + (size_t)(tm + fm * 16 + l15) * FEAT + kb;
            float av[8];
            *(float4*)&av[0] = *(const float4*)ap;
            *(float4*)&av[4] = *(const float4*)(ap + 4);
#pragma unroll
            for (int j = 0; j < 8; ++j) {
                float a = av[j];
                if (USEBN) a = frelu(a * scv[j] + shv[j]);
                const unsigned short hi = bf16_rne(a);
                ah[fm][j] = (short)hi;
                al[fm][j] = (short)bf16_rne(a - bf16_to_f(hi));
            }
        }

        // B fragments: pre-split bf16, contiguous 16B loads
        short8v bh[4], bl[4];
#pragma unroll
        for (int fn = 0; fn < 4; ++fn) {
            const size_t bo = (size_t)(tn + fn * 16 + l15) * FEAT + kb;
            bh[fn] = *(const short8v*)(Bt_hi + bo);
            bl[fn] = *(const short8v*)(Bt_lo + bo);
        }

#pragma unroll
        for (int fm = 0; fm < 4; ++fm)
#pragma unroll
            for (int fn = 0; fn < 4; ++fn) {
                acc[fm][fn] = __builtin_amdgcn_mfma_f32_16x16x32_bf16(
                    ah[fm], bh[fn], acc[fm][fn], 0, 0, 0);
                acc[fm][fn] = __builtin_amdgcn_mfma_f32_16x16x32_bf16(
                    ah[fm], bl[fn], acc[fm][fn], 0, 0, 0);
                acc[fm][fn] = __builtin_amdgcn_mfma_f32_16x16x32_bf16(
                    al[fm], bh[fn], acc[fm][fn], 0, 0, 0);
            }
    }

    // epilogue: D row=(l>>4)*4+reg, col=l&15; scale by dinv[row]; store fp16
#pragma unroll
    for (int fm = 0; fm < 4; ++fm)
#pragma unroll
        for (int r = 0; r < 4; ++r) {
            const int row = tm + fm * 16 + lg * 4 + r;
            const float dv = dinv[row];
            _Float16* cp = C16 + (size_t)row * FEAT + tn + l15;
#pragma unroll
            for (int fn = 0; fn < 4; ++fn)
                cp[fn * 16] = (_Float16)(acc[fm][fn][r] * dv);
        }
}

// ---------------- CSR aggregation: out[v] = dinv[v]*(hs[v] + sum_in hs[u]) + b ------
// hs is fp16 [M][256]; lane covers 4 feats (8B row-slice, 512B/row coalesced).
// fp32 accumulate. 4-way unroll kept (neutral r12, harmless at VGPR 28).
__global__ __launch_bounds__(256) void k_agg(
    const _Float16* __restrict__ hs, const int* __restrict__ rowptr,
    const int* __restrict__ esrc, const float* __restrict__ dinv,
    const float* __restrict__ bias, float* __restrict__ out, int M)
{
    const int wave = threadIdx.x >> 6;
    const int lane = threadIdx.x & 63;
    const int v = blockIdx.x * 4 + wave;
    if (v >= M) return;
    const h16x4* __restrict__ hv = (const h16x4*)hs;
    h16x4 sv = hv[(size_t)v * 64 + lane];                 // self-loop term
    float4 a0, a1, a2, a3;
    a0.x = (float)sv[0]; a0.y = (float)sv[1]; a0.z = (float)sv[2]; a0.w = (float)sv[3];
    a1 = make_float4(0.f, 0.f, 0.f, 0.f);
    a2 = make_float4(0.f, 0.f, 0.f, 0.f);
    a3 = make_float4(0.f, 0.f, 0.f, 0.f);
    const int e0 = rowptr[v], e1 = rowptr[v + 1];
    int e = e0;
    for (; e + 4 <= e1; e += 4) {
        const int u0 = esrc[e + 0];
        const int u1 = esrc[e + 1];
        const int u2 = esrc[e + 2];
        const int u3 = esrc[e + 3];
        const h16x4 m0 = hv[(size_t)u0 * 64 + lane];
        const h16x4 m1 = hv[(size_t)u1 * 64 + lane];
        const h16x4 m2 = hv[(size_t)u2 * 64 + lane];
        const h16x4 m3 = hv[(size_t)u3 * 64 + lane];
        a0.x += (float)m0[0]; a0.y += (float)m0[1]; a0.z += (float)m0[2]; a0.w += (float)m0[3];
        a1.x += (float)m1[0]; a1.y += (float)m1[1]; a1.z += (float)m1[2]; a1.w += (float)m1[3];
        a2.x += (float)m2[0]; a2.y += (float)m2[1]; a2.z += (float)m2[2]; a2.w += (float)m2[3];
        a3.x += (float)m3[0]; a3.y += (float)m3[1]; a3.z += (float)m3[2]; a3.w += (float)m3[3];
    }
    if (e + 2 <= e1) {
        const int u0 = esrc[e + 0];
        const int u1 = esrc[e + 1];
        const h16x4 m0 = hv[(size_t)u0 * 64 + lane];
        const h16x4 m1 = hv[(size_t)u1 * 64 + lane];
        a1.x += (float)m0[0]; a1.y += (float)m0[1]; a1.z += (float)m0[2]; a1.w += (float)m0[3];
        a2.x += (float)m1[0]; a2.y += (float)m1[1]; a2.z += (float)m1[2]; a2.w += (float)m1[3];
        e += 2;
    }
    if (e < e1) {
        const h16x4 m0 = hv[(size_t)esrc[e] * 64 + lane];
        a3.x += (float)m0[0]; a3.y += (float)m0[1]; a3.z += (float)m0[2]; a3.w += (float)m0[3];
    }
    const float dv = dinv[v];
    const float4 bb = ((const float4*)bias)[lane];
    float4 o;
    o.x = (a0.x + a1.x + a2.x + a3.x) * dv + bb.x;
    o.y = (a0.y + a1.y + a2.y + a3.y) * dv + bb.y;
    o.z = (a0.z + a1.z + a2.z + a3.z) * dv + bb.z;
    o.w = (a0.w + a1.w + a2.w + a3.w) * dv + bb.w;
    ((float4*)(out + (size_t)v * FEAT))[lane] = o;
}

// ---------------- BN stats ----------------
__global__ void k_stats(const float* __restrict__ x, int M,
                        float* __restrict__ sum, float* __restrict__ sumsq) {
    const int c = threadIdx.x;
    float s = 0.f, q = 0.f;
    for (int r = blockIdx.x; r < M; r += gridDim.x) {
        const float v = x[(size_t)r * FEAT + c];
        s += v; q += v * v;
    }
    atomicAdd(&sum[c], s);
    atomicAdd(&sumsq[c], q);
}

__global__ void k_bnparams(const float* __restrict__ sum, const float* __restrict__ sumsq,
                           const float* __restrict__ gamma, const float* __restrict__ beta,
                           int M, float* __restrict__ scale, float* __restrict__ shift) {
    const int c = threadIdx.x;
    const float mu = sum[c] / (float)M;
    const float var = sumsq[c] / (float)M - mu * mu;
    const float rstd = rsqrtf(var + BN_EPS);
    const float sc = gamma[c] * rstd;
    scale[c] = sc;
    shift[c] = beta[c] - mu * sc;
}

// ---------------- pooling (batch is sorted): run-length accumulate ----------------
__global__ void k_pool(const float* __restrict__ x, const int* __restrict__ batch,
                       const float* __restrict__ scale, const float* __restrict__ shift,
                       float* __restrict__ pool, int M, int rowsPerBlock) {
    const int c = threadIdx.x;
    int r0 = blockIdx.x * rowsPerBlock;
    int r1 = min(r0 + rowsPerBlock, M);
    if (r0 >= r1) return;
    const float sc = scale[c], sh = shift[c];
    float acc = 0.f;
    int cur = batch[r0];
    for (int r = r0; r < r1; ++r) {
        const int g = batch[r];
        if (g != cur) {
            atomicAdd(&pool[(size_t)cur * FEAT + c], acc);
            acc = 0.f; cur = g;
        }
        acc += frelu(x[(size_t)r * FEAT + c] * sc + sh);
    }
    atomicAdd(&pool[(size_t)cur * FEAT + c], acc);
}

__global__ void k_poolfin(const float* __restrict__ pool, const int* __restrict__ gcnt,
                          float* __restrict__ out) {
    const int g = blockIdx.x, c = threadIdx.x;
    const float cnt = fmaxf((float)gcnt[g], 1.f);
    out[(size_t)g * FEAT + c] = pool[(size_t)g * FEAT + c] / cnt;
}

// ---------------- launch ----------------
extern "C" void kernel_launch(void* const* d_in, const int* in_sizes, int n_in,
                              void* d_out, int out_size, void* d_ws, size_t ws_size,
                              hipStream_t stream) {
    const float* x   = (const float*)d_in[0];
    const int*   ei  = (const int*)d_in[1];
    const int* batch = (const int*)d_in[2];
    const float* W1  = (const float*)d_in[3];
    const float* b1  = (const float*)d_in[4];
    const float* g1  = (const float*)d_in[5];
    const float* be1 = (const float*)d_in[6];
    const float* W2  = (const float*)d_in[7];
    const float* b2  = (const float*)d_in[8];
    const float* g2  = (const float*)d_in[9];
    const float* be2 = (const float*)d_in[10];
    float* out = (float*)d_out;

    const int M = in_sizes[2];          // 40000 nodes (divisible by 64)
    const int E = in_sizes[1] / 2;      // 640000 edges
    const int G = out_size / FEAT;      // 64 graphs
    const int* src_in = ei;
    const int* dst_in = ei + E;

    char* p = (char*)d_ws;
    size_t off = 0;
    auto take = [&](size_t bytes) -> char* {
        char* r = p + off;
        off = (off + bytes + 255) & ~(size_t)255;
        return r;
    };
    _Float16* hsbuf = (_Float16*)take((size_t)M * FEAT * 2);   // fp16 hs (gather table)
    float* bufB  = (float*)take((size_t)M * FEAT * 4);
    int*   esrc  = (int*)take((size_t)E * 4);
    int*   rowptr= (int*)take((size_t)(M + 1) * 4);
    char*  z0 = p + off;                     // ---- zeroed region start ----
    int*   degcnt= (int*)take((size_t)M * 4);
    int*   fillc = (int*)take((size_t)M * 4);
    float* sum1  = (float*)take(FEAT * 4);
    float* sq1   = (float*)take(FEAT * 4);
    float* sum2  = (float*)take(FEAT * 4);
    float* sq2   = (float*)take(FEAT * 4);
    float* pool  = (float*)take((size_t)G * FEAT * 4);
    size_t zbytes = (size_t)((p + off) - z0);  // ---- zeroed region end ----
    int*   gcnt  = (int*)take((size_t)G * 4);
    float* dinv  = (float*)take((size_t)M * 4);
    float* sc1   = (float*)take(FEAT * 4);
    float* sh1   = (float*)take(FEAT * 4);
    float* sc2   = (float*)take(FEAT * 4);
    float* sh2   = (float*)take(FEAT * 4);
    unsigned short* Wt1h = (unsigned short*)take(FEAT * FEAT * 2);
    unsigned short* Wt1l = (unsigned short*)take(FEAT * FEAT * 2);
    unsigned short* Wt2h = (unsigned short*)take(FEAT * FEAT * 2);
    unsigned short* Wt2l = (unsigned short*)take(FEAT * FEAT * 2);
    const int nb = (M + 255) / 256;
    int* bsum = (int*)take((size_t)nb * 4);
    int* boff = (int*)take((size_t)nb * 4);

    hipMemsetAsync(z0, 0, zbytes, stream);

    const int eb = (E + 255) / 256;
    k_count<<<eb, 256, 0, stream>>>(dst_in, E, degcnt);
    k_block_sum<<<nb, 256, 0, stream>>>(degcnt, M, bsum);
    k_scan_bsum<<<1, 256, 0, stream>>>(bsum, nb, boff);
    k_scan_block<<<nb, 256, 0, stream>>>(degcnt, M, boff, rowptr);
    k_fill<<<eb, 256, 0, stream>>>(src_in, dst_in, E, rowptr, fillc, esrc);
    k_dinv<<<nb, 256, 0, stream>>>(degcnt, M, dinv);
    k_gcnt_bs<<<1, 64, 0, stream>>>(batch, M, G, gcnt);
    k_wsplit<<<FEAT, FEAT, 0, stream>>>(W1, Wt1h, Wt1l);
    k_wsplit<<<FEAT, FEAT, 0, stream>>>(W2, Wt2h, Wt2l);

    const int mb = M / 64;   // M=40000 -> 625, exact
    // layer 1
    k_gemm_mfma<0><<<mb, 256, 0, stream>>>(x, Wt1h, Wt1l, nullptr, nullptr, dinv, hsbuf);
    k_agg<<<(M + 3) / 4, 256, 0, stream>>>(hsbuf, rowptr, esrc, dinv, b1, bufB, M);
    k_stats<<<256, 256, 0, stream>>>(bufB, M, sum1, sq1);
    k_bnparams<<<1, 256, 0, stream>>>(sum1, sq1, g1, be1, M, sc1, sh1);
    // layer 2 (BN1+ReLU fused into GEMM2's A-load, before the hi/lo split)
    k_gemm_mfma<1><<<mb, 256, 0, stream>>>(bufB, Wt2h, Wt2l, sc1, sh1, dinv, hsbuf);
    k_agg<<<(M + 3) / 4, 256, 0, stream>>>(hsbuf, rowptr, esrc, dinv, b2, bufB, M);
    k_stats<<<256, 256, 0, stream>>>(bufB, M, sum2, sq2);
    k_bnparams<<<1, 256, 0, stream>>>(sum2, sq2, g2, be2, M, sc2, sh2);
    // BN2+ReLU fused into pooling (1024 blocks: 4/CU occupancy for the 41MB read)
    const int pblocks = 1024;
    const int rpb = (M + pblocks - 1) / pblocks;
    k_pool<<<pblocks, 256, 0, stream>>>(bufB, batch, sc2, sh2, pool, M, rpb);
    k_poolfin<<<G, 256, 0, stream>>>(pool, gcnt, out);
}